// Round 2
// baseline (286.723 us; speedup 1.0000x reference)
//
#include <hip/hip_runtime.h>
#include <hip/hip_bf16.h>
#include <stdint.h>
#include <stddef.h>

typedef __hip_bfloat16 bf16_t;
typedef __attribute__((ext_vector_type(8))) short short8;
typedef __attribute__((ext_vector_type(4))) short short4v;
typedef __attribute__((ext_vector_type(4))) float floatx4;

#define EMBED 1024
#define NHEAD 16
#define HDIM  64
#define BATCH 2
#define SEQ   2048
#define MTOT  (BATCH*SEQ)
#define NEG_INF (-1e30f)
// 1/sqrt(64) * log2(e): softmax carried in exp2 domain
#define SCALE2 0.18033688011112042f

#define MFMA16(a,b,c) __builtin_amdgcn_mfma_f32_16x16x32_bf16(a,b,c,0,0,0)

static __device__ __forceinline__ short bf16_bits(float x) {
    return __builtin_bit_cast(short, __float2bfloat16(x));
}

static __device__ __forceinline__ float fast_exp2(float x) {
#if __has_builtin(__builtin_amdgcn_exp2f)
    return __builtin_amdgcn_exp2f(x);
#else
    return __expf(x * 0.6931471805599453f);
#endif
}

// async global->LDS, 16B per lane; lds ptr must be wave-uniform (HW: base + lane*16)
static __device__ __forceinline__ void async_ld16(const bf16_t* g, short* l) {
    __builtin_amdgcn_global_load_lds(
        (const __attribute__((address_space(1))) void*)g,
        (__attribute__((address_space(3))) void*)l,
        16, 0, 0);
}

static __device__ __forceinline__ void store_out(float* p, float v)  { *p = v; }
static __device__ __forceinline__ void store_out(bf16_t* p, float v) { *p = __float2bfloat16(v); }

// fp32 -> bf16 (RTNE) for q,k,v (4M each) and Wq,Wk,Wv,Wo (1M each). grid.y selects tensor.
__global__ __launch_bounds__(256)
void cvt_all(const float* __restrict__ q, const float* __restrict__ k, const float* __restrict__ v,
             const float* __restrict__ wq, const float* __restrict__ wk,
             const float* __restrict__ wv, const float* __restrict__ wo,
             bf16_t* __restrict__ Qx, bf16_t* __restrict__ Kx, bf16_t* __restrict__ Vx,
             bf16_t* __restrict__ Wqb, bf16_t* __restrict__ Wkb,
             bf16_t* __restrict__ Wvb, bf16_t* __restrict__ Wob)
{
    const float* s; bf16_t* d; int n;
    switch (blockIdx.y) {
        case 0:  s = q;  d = Qx;  n = MTOT * EMBED;  break;
        case 1:  s = k;  d = Kx;  n = MTOT * EMBED;  break;
        case 2:  s = v;  d = Vx;  n = MTOT * EMBED;  break;
        case 3:  s = wq; d = Wqb; n = EMBED * EMBED; break;
        case 4:  s = wk; d = Wkb; n = EMBED * EMBED; break;
        case 5:  s = wv; d = Wvb; n = EMBED * EMBED; break;
        default: s = wo; d = Wob; n = EMBED * EMBED; break;
    }
    const int i4 = (int)blockIdx.x * 256 + (int)threadIdx.x;   // float4 index
    if (i4 * 4 < n) {
        const float4 f = ((const float4*)s)[i4];
        short4v o;
        o[0] = bf16_bits(f.x); o[1] = bf16_bits(f.y);
        o[2] = bf16_bits(f.z); o[3] = bf16_bits(f.w);
        ((short4v*)d)[i4] = o;
    }
}

// C[M,N] = A[M,K] @ W[N,K]^T + bias, bf16 in, fp32 accumulate.
// M=4096, N=K=1024 fixed. 128x128 tile, BK=32, 256 thr (4 waves 2x2). m97 structure.
// VT=true: write output transposed per-batch as Ct[b*1024 + n][s] (for V: [b, d_global, s]).
template <typename OutT, bool VT>
static __device__ __forceinline__ void gemm_tile_128(
    const bf16_t* __restrict__ A, const bf16_t* __restrict__ W,
    const float* __restrict__ bias, OutT* __restrict__ C)
{
    const int N = 1024, K = 1024;
    __shared__ alignas(16) short As[128*32];
    __shared__ alignas(16) short Bs[128*32];

    const int tid  = threadIdx.x;
    const int wave = tid >> 6;
    const int lane = tid & 63;
    const int nbn = N >> 7;                 // 8
    const int bm = (int)blockIdx.x / nbn;
    const int bn = (int)blockIdx.x % nbn;
    const int m0 = bm << 7, n0 = bn << 7;

    const int wm = ((wave >> 1) & 1) << 6;  // 0 / 64
    const int wn = (wave & 1) << 6;

    floatx4 acc[4][4] = {};

    const int srow = (wave << 5) + (lane >> 2);   // staging row within tile
    const int scol = (lane & 3) << 3;             // element col: 0,8,16,24
    const bf16_t* gA = A + (size_t)(m0 + srow) * K + scol;
    const bf16_t* gB = W + (size_t)(n0 + srow) * K + scol;
    short* lA0 = &As[(wave << 10)];
    short* lA1 = &As[(wave << 10) + 512];
    short* lB0 = &Bs[(wave << 10)];
    short* lB1 = &Bs[(wave << 10) + 512];

    const int fr = lane & 15;
    const int fk = (lane >> 4) << 3;

    for (int k0 = 0; k0 < K; k0 += 32) {
        __syncthreads();
        async_ld16(gA,                  lA0);
        async_ld16(gA + (size_t)16 * K, lA1);
        async_ld16(gB,                  lB0);
        async_ld16(gB + (size_t)16 * K, lB1);
        gA += 32; gB += 32;
        __syncthreads();                      // drains vmcnt before barrier (m97-verified)

        short8 af[4], bfr[4];
        #pragma unroll
        for (int i = 0; i < 4; ++i)
            af[i] = *(const short8*)&As[(wm + (i << 4) + fr) * 32 + fk];
        #pragma unroll
        for (int j = 0; j < 4; ++j)
            bfr[j] = *(const short8*)&Bs[(wn + (j << 4) + fr) * 32 + fk];
        #pragma unroll
        for (int i = 0; i < 4; ++i)
            #pragma unroll
            for (int j = 0; j < 4; ++j)
                acc[i][j] = MFMA16(af[i], bfr[j], acc[i][j]);
    }

    // epilogue: C/D layout col=lane&15, row=quad*4+r
    const int q4 = (lane >> 4) << 2;
    #pragma unroll
    for (int j = 0; j < 4; ++j) {
        const int n = n0 + wn + (j << 4) + fr;
        const float bv = bias[n];
        #pragma unroll
        for (int i = 0; i < 4; ++i) {
            const int mb = m0 + wm + (i << 4) + q4;
            if (VT) {
                // transposed store: Ct[(b*1024 + n)][s], s = mb&2047 .. +3 contiguous (8B)
                const int bb = mb >> 11, ss = mb & 2047;
                short4v pk;
                #pragma unroll
                for (int r = 0; r < 4; ++r)
                    pk[r] = bf16_bits(acc[i][j][r] + bv);
                *(short4v*)((bf16_t*)C + ((size_t)(bb * 1024 + n) << 11) + ss) = pk;
            } else {
                #pragma unroll
                for (int r = 0; r < 4; ++r)
                    store_out(&C[(size_t)(mb + r) * N + n], acc[i][j][r] + bv);
            }
        }
    }
}

__global__ __launch_bounds__(256)
void qkv_proj(const bf16_t* __restrict__ xq, const bf16_t* __restrict__ xk,
              const bf16_t* __restrict__ xv,
              const bf16_t* __restrict__ Wq, const bf16_t* __restrict__ Wk,
              const bf16_t* __restrict__ Wv,
              const float* __restrict__ bq, const float* __restrict__ bk,
              const float* __restrict__ bv,
              bf16_t* __restrict__ Qp, bf16_t* __restrict__ Kp, bf16_t* __restrict__ Vtp)
{
    if (blockIdx.z == 0)      gemm_tile_128<bf16_t, false>(xq, Wq, bq, Qp);
    else if (blockIdx.z == 1) gemm_tile_128<bf16_t, false>(xk, Wk, bk, Kp);
    else                      gemm_tile_128<bf16_t, true >(xv, Wv, bv, Vtp);
}

__global__ __launch_bounds__(256)
void out_proj(const bf16_t* __restrict__ AO, const bf16_t* __restrict__ Wo,
              const float* __restrict__ bo, float* __restrict__ out)
{
    gemm_tile_128<float, false>(AO, Wo, bo, out);
}

// Flash attention, causal, S^T formulation (D = K·Q^T, one q-row per lane column).
// v3 changes (latency-chain surgery + kv-split):
//  - NO cross-lane ops in the hot loop: max is quad-local + __any ballot gate
//    (full shfl-reduce + O-rescale only on the rare need-path, ~once/wave);
//    l is a per-lane partial, reduced across quads ONCE in the epilogue.
//    Hot-loop DS chain is just the P write->read round-trip.
//  - kv-split: tiles 32..63 are processed by 2 waves (halves of the kv range),
//    each writing fp32 partials (unnormalized O, m, l) combined by attn_combine.
//    Longest wave: 64 -> 32 iters; 3072 single-wave blocks, all resident.
//  - partials overlay dead workspace (Qx+Kx for O, Wqb for m/l).
__global__ __launch_bounds__(64)
void attn_causal(const bf16_t* __restrict__ Qp, const bf16_t* __restrict__ Kp,
                 const bf16_t* __restrict__ Vt, bf16_t* __restrict__ AO,
                 float* __restrict__ Op, float* __restrict__ Mp, float* __restrict__ Lp)
{
    __shared__ alignas(16) short Pbuf[2][16 * 40];   // padded stride 40 (80B rows)

    const int lane = (int)threadIdx.x & 63;
    const int bid  = (int)blockIdx.x;
    const int bh   = bid & 31;           // bh%8 == XCD for all blocks of this head
    const int w    = bid >> 5;           // 0..95 work-slot, longest-first
    int tile, sidx, c0, c1;
    bool split;
    if (w < 64) {                        // split tiles 63..32, two waves each
        tile  = 63 - (w >> 1);
        sidx  = w & 1;
        split = true;
        const int nch = tile + 1;
        const int h1  = (nch + 1) >> 1;
        c0 = sidx ? h1 : 0;
        c1 = sidx ? nch : h1;
    } else {                             // single-wave tiles 31..0
        tile  = 95 - w;
        sidx  = 0;
        split = false;
        c0 = 0;
        c1 = tile + 1;
    }
    const bool hasdiag = (c1 == tile + 1);
    const int b = bh >> 4, h = bh & 15;
    const int q0 = tile << 5;

    const int fr   = lane & 15;
    const int quad = lane >> 4;
    const int fk   = quad << 3;

    // Q B-frags (B[k=d][n=q]) for both 16-row subtiles
    const bf16_t* Q0 = Qp + (size_t)(b * SEQ + q0 + fr) * EMBED + h * HDIM;
    const short8 aq00 = *(const short8*)(Q0 + fk);
    const short8 aq01 = *(const short8*)(Q0 + 32 + fk);
    const short8 aq10 = *(const short8*)(Q0 + (size_t)16 * EMBED + fk);
    const short8 aq11 = *(const short8*)(Q0 + (size_t)16 * EMBED + 32 + fk);

    const bf16_t* Kbase = Kp + (size_t)(b * SEQ) * EMBED + h * HDIM;
    const bf16_t* Vbase = Vt + ((size_t)(b * 1024 + h * HDIM) << 11);

    floatx4 o0[4] = {}, o1[4] = {};      // O[q=quad*4+r][d=t*16+fr], per subtile
    float m0 = NEG_INF, m1 = NEG_INF;    // running max (log2 domain), uniform per q-col
    float l0 = 0.f, l1 = 0.f;            // PER-LANE partial sums (reduced in epilogue)

    short* Pw0 = &Pbuf[0][0];
    short* Pw1 = &Pbuf[1][0];

    // Softmax values for one subtile; NO cross-lane ops on the common path.
    // sA[r] = S[kv0+quad*4+r][q], sB[r] = S[kv0+16+quad*4+r][q], q = u16+fr.
    auto smax_vals = [&](const floatx4& sA, const floatx4& sB, float& m_u, float& l_u,
                         floatx4* o_u, const bool diag, const int u16,
                         float* v0, float* v1) {
        float mx = NEG_INF;
        #pragma unroll
        for (int r = 0; r < 4; ++r) {
            float a  = sA[r] * SCALE2;
            float bb = sB[r] * SCALE2;
            if (diag) {                           // diag chunk: kv0 == q0 exactly
                const int kq = (quad << 2) + r;
                const int lq = u16 + fr;
                if (kq > lq)      a  = NEG_INF;
                if (kq + 16 > lq) bb = NEG_INF;
            }
            v0[r] = a; v1[r] = bb;
            mx = fmaxf(mx, fmaxf(a, bb));
        }
        // defer-max gate: quad-local max vs running max (ballot, no DS ops)
        if (__any(mx > m_u + 8.0f)) {             // rare path (~once per wave)
            mx = fmaxf(mx, __shfl_xor(mx, 16, 64));
            mx = fmaxf(mx, __shfl_xor(mx, 32, 64));
            const float mn = fmaxf(m_u, mx);
            const float al = fast_exp2(m_u - mn);
            m_u = mn;
            l_u *= al;                            // per-lane partial scales uniformly
            #pragma unroll
            for (int r = 0; r < 4; ++r) {
                const float ao = __shfl(al, (lane & 48) | ((quad << 2) + r), 64);
                #pragma unroll
                for (int t = 0; t < 4; ++t) o_u[t][r] *= ao;
            }
        }
        float ls = 0.f;
        #pragma unroll
        for (int r = 0; r < 4; ++r) {
            v0[r] = fast_exp2(v0[r] - m_u);       // bounded by 2^8 (defer-max)
            v1[r] = fast_exp2(v1[r] - m_u);
            ls += v0[r] + v1[r];
        }
        l_u += ls;                                // per-lane partial, no shfl
    };

#define KLOAD(K0_, K1_, K2_, K3_, kvo) do {                                  \
        const bf16_t* Kr0_ = Kbase + (size_t)((kvo) + fr) * EMBED;           \
        const bf16_t* Kr1_ = Kr0_ + (size_t)16 * EMBED;                      \
        K0_ = *(const short8*)(Kr0_ + fk);                                   \
        K1_ = *(const short8*)(Kr0_ + 32 + fk);                              \
        K2_ = *(const short8*)(Kr1_ + fk);                                   \
        K3_ = *(const short8*)(Kr1_ + 32 + fk);                              \
    } while (0)

#define ITER(KC0, KC1, KC2, KC3, KN0, KN1, KN2, KN3, DIAGF, PREF) do {       \
        const int kv0 = c << 5;                                              \
        /* V issued first: consumed only after softmax (latency hidden) */   \
        const short8 vf0 = *(const short8*)(Vbase + ((size_t)(fr)      << 11) + kv0 + fk); \
        const short8 vf1 = *(const short8*)(Vbase + ((size_t)(16 + fr) << 11) + kv0 + fk); \
        const short8 vf2 = *(const short8*)(Vbase + ((size_t)(32 + fr) << 11) + kv0 + fk); \
        const short8 vf3 = *(const short8*)(Vbase + ((size_t)(48 + fr) << 11) + kv0 + fk); \
        floatx4 s00 = {}, s01 = {}, s10 = {}, s11 = {};                      \
        s00 = MFMA16(KC0, aq00, s00); s00 = MFMA16(KC1, aq01, s00);          \
        s10 = MFMA16(KC0, aq10, s10); s10 = MFMA16(KC1, aq11, s10);          \
        s01 = MFMA16(KC2, aq00, s01); s01 = MFMA16(KC3, aq01, s01);          \
        s11 = MFMA16(KC2, aq10, s11); s11 = MFMA16(KC3, aq11, s11);          \
        if (PREF) { KLOAD(KN0, KN1, KN2, KN3, kv0 + 32); }                   \
        float p00[4], p01[4], p10[4], p11[4];                                \
        smax_vals(s00, s01, m0, l0, o0, DIAGF, 0,  p00, p01);                \
        smax_vals(s10, s11, m1, l1, o1, DIAGF, 16, p10, p11);                \
        short4v wa0, wa1, wb0, wb1;                                          \
        _Pragma("unroll")                                                    \
        for (int r = 0; r < 4; ++r) {                                        \
            wa0[r] = bf16_bits(p00[r]); wa1[r] = bf16_bits(p01[r]);          \
            wb0[r] = bf16_bits(p10[r]); wb1[r] = bf16_bits(p11[r]);          \
        }                                                                    \
        *(short4v*)&Pw0[fr * 40 + (quad << 2)]      = wa0;                   \
        *(short4v*)&Pw0[fr * 40 + 16 + (quad << 2)] = wa1;                   \
        *(short4v*)&Pw1[fr * 40 + (quad << 2)]      = wb0;                   \
        *(short4v*)&Pw1[fr * 40 + 16 + (quad << 2)] = wb1;                   \
        __asm__ volatile("" ::: "memory");   /* same-wave DS is in-order */  \
        const short8 pa0 = *(const short8*)&Pw0[fr * 40 + fk];               \
        const short8 pa1 = *(const short8*)&Pw1[fr * 40 + fk];               \
        __asm__ volatile("" ::: "memory");                                   \
        o0[0] = MFMA16(pa0, vf0, o0[0]); o1[0] = MFMA16(pa1, vf0, o1[0]);    \
        o0[1] = MFMA16(pa0, vf1, o0[1]); o1[1] = MFMA16(pa1, vf1, o1[1]);    \
        o0[2] = MFMA16(pa0, vf2, o0[2]); o1[2] = MFMA16(pa1, vf2, o1[2]);    \
        o0[3] = MFMA16(pa0, vf3, o0[3]); o1[3] = MFMA16(pa1, vf3, o1[3]);    \
    } while (0)

    short8 ka0, ka1, ka2, ka3, kb0, kb1, kb2, kb3;
    KLOAD(ka0, ka1, ka2, ka3, c0 << 5);

    int c = c0;
    const int cl = c1 - 1;
    if (cl > c0) {
        for (;;) {                               // hot loop: no mask code
            ITER(ka0, ka1, ka2, ka3, kb0, kb1, kb2, kb3, false, true);
            if (++c == cl) break;
            ITER(kb0, kb1, kb2, kb3, ka0, ka1, ka2, ka3, false, true);
            if (++c == cl) break;
        }
    }
    // last chunk (diagonal iff this wave owns the tile's end)
    if ((c - c0) & 1) { ITER(kb0, kb1, kb2, kb3, ka0, ka1, ka2, ka3, hasdiag, false); }
    else              { ITER(ka0, ka1, ka2, ka3, kb0, kb1, kb2, kb3, hasdiag, false); }

#undef ITER
#undef KLOAD

    // deferred cross-quad l reduction (once)
    { float t = __shfl_xor(l0, 16, 64); l0 += t; t = __shfl_xor(l0, 32, 64); l0 += t; }
    { float t = __shfl_xor(l1, 16, 64); l1 += t; t = __shfl_xor(l1, 32, 64); l1 += t; }

    if (!split) {
        // normalize + store
        const float r0 = 1.0f / l0;
        const float r1 = 1.0f / l1;
        #pragma unroll
        for (int r = 0; r < 4; ++r) {
            const int src = (lane & 48) | ((quad << 2) + r);
            const float i0 = __shfl(r0, src, 64);
            const float i1 = __shfl(r1, src, 64);
            const int row0 = q0 + (quad << 2) + r;
            bf16_t* out0 = AO + (size_t)(b * SEQ + row0) * EMBED + h * HDIM + fr;
            bf16_t* out1 = out0 + (size_t)16 * EMBED;
            #pragma unroll
            for (int t = 0; t < 4; ++t) {
                out0[t << 4] = __float2bfloat16(o0[t][r] * i0);
                out1[t << 4] = __float2bfloat16(o1[t][r] * i1);
            }
        }
    } else {
        // fp32 partial store: Op[s][p][row][d], m/l per row
        const int p = (bh << 5) | (tile - 32);            // 0..1023
        float* Ob = Op + (((size_t)sidx << 10) + p) * 2048;
        #pragma unroll
        for (int r = 0; r < 4; ++r) {
            const int row0 = (quad << 2) + r;
            #pragma unroll
            for (int t = 0; t < 4; ++t) {
                Ob[row0 * 64 + (t << 4) + fr]        = o0[t][r];
                Ob[(16 + row0) * 64 + (t << 4) + fr] = o1[t][r];
            }
        }
        if (quad == 0) {                                  // m,l uniform across quads
            const size_t mb = (((size_t)sidx << 10) + p) * 32;
            Mp[mb + fr]      = m0;
            Mp[mb + 16 + fr] = m1;
            Lp[mb + fr]      = l0;
            Lp[mb + 16 + fr] = l1;
        }
    }
}

// Combine the two kv-half partials of split tiles: O = (O0*w0 + O1*w1)/(l0*w0 + l1*w1),
// w_s = 2^(m_s - M), M = max(m0,m1). One block per tile-instance (p in 0..1023).
__global__ __launch_bounds__(256)
void attn_combine(const float* __restrict__ Op, const float* __restrict__ Mp,
                  const float* __restrict__ Lp, bf16_t* __restrict__ AO)
{
    const int p   = (int)blockIdx.x;          // (bh<<5)|(tile-32)
    const int tid = (int)threadIdx.x;
    const int row = tid >> 3;                 // 0..31
    const int d0  = (tid & 7) << 3;           // 0,8,..,56
    const int bh = p >> 5, tile = 32 + (p & 31);
    const int b = bh >> 4, h = bh & 15;

    const float m0 = Mp[(size_t)p * 32 + row];
    const float m1 = Mp[(size_t)(1024 + p) * 32 + row];
    const float l0 = Lp[(size_t)p * 32 + row];
    const float l1 = Lp[(size_t)(1024 + p) * 32 + row];
    const float M  = fmaxf(m0, m1);
    const float w0 = fast_exp2(m0 - M);
    const float w1 = fast_exp2(m1 - M);
    const float rd = 1.0f / (l0 * w0 + l1 * w1);

    const float* O0 = Op + ((size_t)p << 11) + row * 64 + d0;
    const float* O1 = O0 + ((size_t)1024 << 11);
    const float4 a0 = *(const float4*)O0;
    const float4 a1 = *(const float4*)(O0 + 4);
    const float4 c0 = *(const float4*)O1;
    const float4 c1 = *(const float4*)(O1 + 4);

    short8 pk;
    pk[0] = bf16_bits((a0.x * w0 + c0.x * w1) * rd);
    pk[1] = bf16_bits((a0.y * w0 + c0.y * w1) * rd);
    pk[2] = bf16_bits((a0.z * w0 + c0.z * w1) * rd);
    pk[3] = bf16_bits((a0.w * w0 + c0.w * w1) * rd);
    pk[4] = bf16_bits((a1.x * w0 + c1.x * w1) * rd);
    pk[5] = bf16_bits((a1.y * w0 + c1.y * w1) * rd);
    pk[6] = bf16_bits((a1.z * w0 + c1.z * w1) * rd);
    pk[7] = bf16_bits((a1.w * w0 + c1.w * w1) * rd);
    *(short8*)(AO + (size_t)(b * SEQ + tile * 32 + row) * EMBED + h * HDIM + d0) = pk;
}

extern "C" void kernel_launch(void* const* d_in, const int* in_sizes, int n_in,
                              void* d_out, int out_size, void* d_ws, size_t ws_size,
                              hipStream_t stream)
{
    (void)in_sizes; (void)n_in; (void)out_size; (void)ws_size;
    const float* q  = (const float*)d_in[0];
    const float* k  = (const float*)d_in[1];
    const float* v  = (const float*)d_in[2];
    const float* Wq = (const float*)d_in[3];
    const float* bq = (const float*)d_in[4];
    const float* Wk = (const float*)d_in[5];
    const float* bk = (const float*)d_in[6];
    const float* Wv = (const float*)d_in[7];
    const float* bv = (const float*)d_in[8];
    const float* Wo = (const float*)d_in[9];
    const float* bo = (const float*)d_in[10];
    // d_in[11] = attn_mask: fixed causal tril, handled analytically.

    const size_t NX = (size_t)MTOT * EMBED;   // 4M
    const size_t NW = (size_t)EMBED * EMBED;  // 1M
    bf16_t* Qx  = (bf16_t*)d_ws;
    bf16_t* Kx  = Qx  + NX;
    bf16_t* Vx  = Kx  + NX;
    bf16_t* Wqb = Vx  + NX;
    bf16_t* Wkb = Wqb + NW;
    bf16_t* Wvb = Wkb + NW;
    bf16_t* Wob = Wvb + NW;
    bf16_t* Qp  = Wob + NW;
    bf16_t* Kp  = Qp  + NX;
    bf16_t* Vtp = Kp  + NX;   // transposed: [b*1024 + d_global][s]
    bf16_t* AO  = Vtp + NX;   // total 32M bf16 = 64 MB

    // attn partials overlay buffers that are dead after qkv_proj:
    //   Op (16 MB fp32) over Qx+Kx; Mp/Lp (512 KB) over Wqb.
    float* Op = (float*)Qx;
    float* Mp = (float*)Wqb;
    float* Lp = Mp + 2 * 1024 * 32;

    dim3 blk(256);
    cvt_all<<<dim3(4096, 7), blk, 0, stream>>>(q, k, v, Wq, Wk, Wv, Wo,
                                               Qx, Kx, Vx, Wqb, Wkb, Wvb, Wob);
    qkv_proj<<<dim3(256, 1, 3), blk, 0, stream>>>(Qx, Kx, Vx, Wqb, Wkb, Wvb,
                                                  bq, bk, bv, Qp, Kp, Vtp);
    attn_causal<<<dim3(3072), dim3(64), 0, stream>>>(Qp, Kp, Vtp, AO, Op, Mp, Lp);
    attn_combine<<<dim3(1024), blk, 0, stream>>>(Op, Mp, Lp, AO);
    out_proj<<<dim3(256), blk, 0, stream>>>(AO, Wob, bo, (float*)d_out);
}

// Round 4
// 284.084 us; speedup vs baseline: 1.0093x; 1.0093x over previous
//
#include <hip/hip_runtime.h>
#include <hip/hip_bf16.h>
#include <stdint.h>
#include <stddef.h>

typedef __hip_bfloat16 bf16_t;
typedef __attribute__((ext_vector_type(8))) short short8;
typedef __attribute__((ext_vector_type(4))) short short4v;
typedef __attribute__((ext_vector_type(4))) float floatx4;
typedef __attribute__((ext_vector_type(4))) unsigned uint4v;
typedef __attribute__((ext_vector_type(2))) unsigned uint2v;

#define EMBED 1024
#define NHEAD 16
#define HDIM  64
#define BATCH 2
#define SEQ   2048
#define MTOT  (BATCH*SEQ)
#define NEG_INF (-1e30f)
// 1/sqrt(64) * log2(e): softmax carried in exp2 domain (folded into Q projection)
#define SCALE2 0.18033688011112042f

#define MFMA16(a,b,c) __builtin_amdgcn_mfma_f32_16x16x32_bf16(a,b,c,0,0,0)

static __device__ __forceinline__ short bf16_bits(float x) {
    return __builtin_bit_cast(short, __float2bfloat16(x));
}

static __device__ __forceinline__ float fast_exp2(float x) {
#if __has_builtin(__builtin_amdgcn_exp2f)
    return __builtin_amdgcn_exp2f(x);
#else
    return __expf(x * 0.6931471805599453f);
#endif
}

// two bf16 (RTNE) packed in a u32; compiler fuses to v_cvt_pk_bf16_f32 (m240)
static __device__ __forceinline__ unsigned pack_bf16x2(float lo, float hi) {
    const unsigned a = (unsigned)(unsigned short)bf16_bits(lo);
    const unsigned b = (unsigned)(unsigned short)bf16_bits(hi);
    return a | (b << 16);
}

// gfx950 permlane swaps. Semantics (ISA):
//  p32: new_a[lane] = (lane&32) ? old_b[lane-32] : old_a[lane];
//       new_b[lane] = (lane&32) ? old_b[lane]    : old_a[lane+32]
//  p16: same with row-16 (bit 4) pairing.
static __device__ __forceinline__ void permswap32(unsigned& a, unsigned& b) {
#if __has_builtin(__builtin_amdgcn_permlane32_swap)
    uint2v r = __builtin_amdgcn_permlane32_swap(a, b, false, false);
    a = r[0]; b = r[1];
#else
    asm volatile("v_permlane32_swap_b32 %0, %1" : "+v"(a), "+v"(b));
#endif
}
static __device__ __forceinline__ void permswap16(unsigned& a, unsigned& b) {
#if __has_builtin(__builtin_amdgcn_permlane16_swap)
    uint2v r = __builtin_amdgcn_permlane16_swap(a, b, false, false);
    a = r[0]; b = r[1];
#else
    asm volatile("v_permlane16_swap_b32 %0, %1" : "+v"(a), "+v"(b));
#endif
}

// async global->LDS, 16B per lane; lds ptr must be wave-uniform (HW: base + lane*16)
static __device__ __forceinline__ void async_ld16(const bf16_t* g, short* l) {
    __builtin_amdgcn_global_load_lds(
        (const __attribute__((address_space(1))) void*)g,
        (__attribute__((address_space(3))) void*)l,
        16, 0, 0);
}

static __device__ __forceinline__ void store_out(float* p, float v)  { *p = v; }
static __device__ __forceinline__ void store_out(bf16_t* p, float v) { *p = __float2bfloat16(v); }

// fp32 -> bf16 (RTNE) for q,k,v (4M each) and Wq,Wk,Wv,Wo (1M each). grid.y selects tensor.
__global__ __launch_bounds__(256)
void cvt_all(const float* __restrict__ q, const float* __restrict__ k, const float* __restrict__ v,
             const float* __restrict__ wq, const float* __restrict__ wk,
             const float* __restrict__ wv, const float* __restrict__ wo,
             bf16_t* __restrict__ Qx, bf16_t* __restrict__ Kx, bf16_t* __restrict__ Vx,
             bf16_t* __restrict__ Wqb, bf16_t* __restrict__ Wkb,
             bf16_t* __restrict__ Wvb, bf16_t* __restrict__ Wob)
{
    const float* s; bf16_t* d; int n;
    switch (blockIdx.y) {
        case 0:  s = q;  d = Qx;  n = MTOT * EMBED;  break;
        case 1:  s = k;  d = Kx;  n = MTOT * EMBED;  break;
        case 2:  s = v;  d = Vx;  n = MTOT * EMBED;  break;
        case 3:  s = wq; d = Wqb; n = EMBED * EMBED; break;
        case 4:  s = wk; d = Wkb; n = EMBED * EMBED; break;
        case 5:  s = wv; d = Wvb; n = EMBED * EMBED; break;
        default: s = wo; d = Wob; n = EMBED * EMBED; break;
    }
    const int i4 = (int)blockIdx.x * 256 + (int)threadIdx.x;   // float4 index
    if (i4 * 4 < n) {
        const float4 f = ((const float4*)s)[i4];
        short4v o;
        o[0] = bf16_bits(f.x); o[1] = bf16_bits(f.y);
        o[2] = bf16_bits(f.z); o[3] = bf16_bits(f.w);
        ((short4v*)d)[i4] = o;
    }
}

// C[M,N] = (A[M,K] @ W[N,K]^T + bias) * scale, bf16 in, fp32 accumulate.
// M=4096, N=K=1024 fixed. BM x 128 tile, BK=32, 256 thr (4 waves 2x2). m97 structure.
// BM=128 for qkv (3 blocks/CU), BM=64 for out_proj (512 blocks -> 2 blocks/CU).
// VT=true: write output transposed per-batch as Ct[b*1024 + n][s] (for V: [b, d_global, s]).
template <typename OutT, bool VT, int BM>
static __device__ __forceinline__ void gemm_tile(
    const bf16_t* __restrict__ A, const bf16_t* __restrict__ W,
    const float* __restrict__ bias, OutT* __restrict__ C, const float scale)
{
    constexpr int MI = BM >> 5;             // A-frags per wave (4 or 2)
    constexpr int RPW = BM >> 2;            // A rows staged per wave
    const int N = 1024, K = 1024;
    __shared__ alignas(16) short As[BM * 32];
    __shared__ alignas(16) short Bs[128 * 32];

    const int tid  = threadIdx.x;
    const int wave = tid >> 6;
    const int lane = tid & 63;
    const int bm = (int)blockIdx.x >> 3;    // nbn = 8
    const int bn = (int)blockIdx.x & 7;
    const int m0 = bm * BM, n0 = bn << 7;

    const int wm = ((wave >> 1) & 1) * (BM >> 1);
    const int wn = (wave & 1) << 6;

    floatx4 acc[MI][4] = {};

    const int srowA = wave * RPW + (lane >> 2);
    const int srowB = (wave << 5) + (lane >> 2);
    const int scol  = (lane & 3) << 3;            // element col: 0,8,16,24
    const bf16_t* gA = A + (size_t)(m0 + srowA) * K + scol;
    const bf16_t* gB = W + (size_t)(n0 + srowB) * K + scol;
    short* lA0 = &As[wave * RPW * 32];
    short* lA1 = lA0 + 512;
    short* lB0 = &Bs[(wave << 10)];
    short* lB1 = lB0 + 512;

    const int fr = lane & 15;
    const int fk = (lane >> 4) << 3;

    for (int k0 = 0; k0 < K; k0 += 32) {
        __syncthreads();
        async_ld16(gA, lA0);
        if constexpr (BM == 128) async_ld16(gA + (size_t)16 * K, lA1);
        async_ld16(gB, lB0);
        async_ld16(gB + (size_t)16 * K, lB1);
        gA += 32; gB += 32;
        __syncthreads();                      // drains vmcnt before barrier (m97-verified)

        short8 af[MI], bfr[4];
        #pragma unroll
        for (int i = 0; i < MI; ++i)
            af[i] = *(const short8*)&As[(wm + (i << 4) + fr) * 32 + fk];
        #pragma unroll
        for (int j = 0; j < 4; ++j)
            bfr[j] = *(const short8*)&Bs[(wn + (j << 4) + fr) * 32 + fk];
        #pragma unroll
        for (int i = 0; i < MI; ++i)
            #pragma unroll
            for (int j = 0; j < 4; ++j)
                acc[i][j] = MFMA16(af[i], bfr[j], acc[i][j]);
    }

    // epilogue: C/D layout col=lane&15, row=quad*4+r
    const int q4 = (lane >> 4) << 2;
    #pragma unroll
    for (int j = 0; j < 4; ++j) {
        const int n = n0 + wn + (j << 4) + fr;
        const float bv = bias[n];
        #pragma unroll
        for (int i = 0; i < MI; ++i) {
            const int mb = m0 + wm + (i << 4) + q4;
            if (VT) {
                // transposed store: Ct[(b*1024 + n)][s], s = mb&2047 .. +3 contiguous (8B)
                const int bb = mb >> 11, ss = mb & 2047;
                short4v pk;
                #pragma unroll
                for (int r = 0; r < 4; ++r)
                    pk[r] = bf16_bits((acc[i][j][r] + bv) * scale);
                *(short4v*)((bf16_t*)C + ((size_t)(bb * 1024 + n) << 11) + ss) = pk;
            } else {
                #pragma unroll
                for (int r = 0; r < 4; ++r)
                    store_out(&C[(size_t)(mb + r) * N + n], (acc[i][j][r] + bv) * scale);
            }
        }
    }
}

__global__ __launch_bounds__(256)
void qkv_proj(const bf16_t* __restrict__ xq, const bf16_t* __restrict__ xk,
              const bf16_t* __restrict__ xv,
              const bf16_t* __restrict__ Wq, const bf16_t* __restrict__ Wk,
              const bf16_t* __restrict__ Wv,
              const float* __restrict__ bq, const float* __restrict__ bk,
              const float* __restrict__ bv,
              bf16_t* __restrict__ Qp, bf16_t* __restrict__ Kp, bf16_t* __restrict__ Vtp)
{
    // Q carries the softmax scale (exp2-domain): folded here, free in attn hot loop
    if (blockIdx.z == 0)      gemm_tile<bf16_t, false, 128>(xq, Wq, bq, Qp, SCALE2);
    else if (blockIdx.z == 1) gemm_tile<bf16_t, false, 128>(xk, Wk, bk, Kp, 1.0f);
    else                      gemm_tile<bf16_t, true , 128>(xv, Wv, bv, Vtp, 1.0f);
}

__global__ __launch_bounds__(256)
void out_proj(const bf16_t* __restrict__ AO, const bf16_t* __restrict__ Wo,
              const float* __restrict__ bo, float* __restrict__ out)
{
    gemm_tile<float, false, 64>(AO, Wo, bo, out, 1.0f);
}

// Flash attention, causal. QK^T computed as S^T = K·Q^T (C-layout: q = lane&15).
// v4: ZERO LDS, zero hot-loop cross-lane latency ops:
//  - PV computed as O^T = V^T·P^T. The B-operand (P^T[kv][q]) is built from the
//    S^T C-layout fragments by a pure quad-permutation: cvt_pk bf16 pairs, then
//    2x permlane32_swap + 2x permlane16_swap per subtile (gfx950 builtins).
//    Replaces the LDS write->read round-trip entirely.
//  - O^T layout: every accumulator value has q = lane&15 -> alpha-rescale and
//    1/l normalize are per-lane multiplies (no shfl broadcasts); stores are 8B.
//  - max gate: quad-local max + __any ballot; full reduce only on rare need-path.
//  - l kept as per-lane partial, reduced across quads once in epilogue.
//  - K(c+1) prefetched at iteration TOP (full-iter latency cover); V(c) at top too.
//  - kv-split (R2): tiles 32..63 processed by 2 waves writing fp32 partials.
// Vt layout: Vt[(b*1024 + h*64 + d)][s] (written by qkv_proj VT epilogue).
__global__ __launch_bounds__(64)
void attn_causal(const bf16_t* __restrict__ Qp, const bf16_t* __restrict__ Kp,
                 const bf16_t* __restrict__ Vt, bf16_t* __restrict__ AO,
                 float* __restrict__ Op, float* __restrict__ Mp, float* __restrict__ Lp)
{
    const int lane = (int)threadIdx.x & 63;
    const int bid  = (int)blockIdx.x;
    const int bh   = bid & 31;           // bh%8 == XCD for all blocks of this head
    const int w    = bid >> 5;           // 0..95 work-slot, longest-first
    int tile, sidx, c0, c1;
    bool split;
    if (w < 64) {                        // split tiles 63..32, two waves each
        tile  = 63 - (w >> 1);
        sidx  = w & 1;
        split = true;
        const int nch = tile + 1;
        const int h1  = (nch + 1) >> 1;
        c0 = sidx ? h1 : 0;
        c1 = sidx ? nch : h1;
    } else {                             // single-wave tiles 31..0
        tile  = 95 - w;
        sidx  = 0;
        split = false;
        c0 = 0;
        c1 = tile + 1;
    }
    const bool hasdiag = (c1 == tile + 1);
    const int b = bh >> 4, h = bh & 15;
    const int q0 = tile << 5;

    const int fr   = lane & 15;
    const int quad = lane >> 4;
    const int fk   = quad << 3;

    // Q B-frags (B[k=d][n=q]) for both 16-row subtiles (Q pre-scaled by SCALE2)
    const bf16_t* Q0 = Qp + (size_t)(b * SEQ + q0 + fr) * EMBED + h * HDIM;
    const short8 aq00 = *(const short8*)(Q0 + fk);
    const short8 aq01 = *(const short8*)(Q0 + 32 + fk);
    const short8 aq10 = *(const short8*)(Q0 + (size_t)16 * EMBED + fk);
    const short8 aq11 = *(const short8*)(Q0 + (size_t)16 * EMBED + 32 + fk);

    const bf16_t* Kbase = Kp + (size_t)(b * SEQ) * EMBED + h * HDIM;
    const bf16_t* Vbase = Vt + ((size_t)(b * 1024 + h * HDIM) << 11);

    floatx4 o0[4] = {}, o1[4] = {};      // O^T[d=t*16+quad*4+r][q=fr], per subtile
    float m0 = NEG_INF, m1 = NEG_INF;    // running max (log2 domain), per q=fr
    float l0 = 0.f, l1 = 0.f;            // per-lane partials (reduced in epilogue)

    // Softmax for one subtile -> PV B-frag (P^T[kv][q]) via permlane quad-transpose.
    // In:  sA[r] = S[kv0+quad*4+r][q=fr], sB[r] = S[kv0+16+quad*4+r][q=fr].
    // Out: short8 with word w = bf16 pair P[kv = quad*8 + 2w, +1][q=fr].
    auto smax_pb = [&](const floatx4& sA, const floatx4& sB, float& m_u, float& l_u,
                       floatx4* o_u, const bool diag, const int u16) -> short8 {
        float v0[4], v1[4];
        #pragma unroll
        for (int r = 0; r < 4; ++r) {
            float a  = sA[r];
            float bb = sB[r];
            if (diag) {                           // diag chunk: kv0 == q0 exactly
                const int kq = (quad << 2) + r;
                const int lq = u16 + fr;
                if (kq > lq)      a  = NEG_INF;
                if (kq + 16 > lq) bb = NEG_INF;
            }
            v0[r] = a; v1[r] = bb;
        }
        float mx = fmaxf(fmaxf(fmaxf(v0[0], v0[1]), fmaxf(v0[2], v0[3])),
                         fmaxf(fmaxf(v1[0], v1[1]), fmaxf(v1[2], v1[3])));
        // defer-max gate: quad-local max vs running max (ballot, no cross-lane data)
        if (__any(mx > m_u + 8.0f)) {             // rare path (~once per wave)
            mx = fmaxf(mx, __shfl_xor(mx, 16, 64));
            mx = fmaxf(mx, __shfl_xor(mx, 32, 64));
            const float mn = fmaxf(m_u, mx);
            const float al = fast_exp2(m_u - mn);
            m_u = mn;
            l_u *= al;
            #pragma unroll
            for (int t = 0; t < 4; ++t)           // O^T: q = fr for ALL values
                #pragma unroll
                for (int r = 0; r < 4; ++r) o_u[t][r] *= al;
        }
        float ls = 0.f;
        #pragma unroll
        for (int r = 0; r < 4; ++r) {
            v0[r] = fast_exp2(v0[r] - m_u);       // bounded by 2^8 (defer-max)
            v1[r] = fast_exp2(v1[r] - m_u);
            ls += v0[r] + v1[r];
        }
        l_u += ls;                                // per-lane partial, no shfl
        // pack P pairs: lane(fr,quad) holds kv {4q+0,4q+1},{4q+2,4q+3},{16+...}
        unsigned c0p = pack_bf16x2(v0[0], v0[1]);
        unsigned c1p = pack_bf16x2(v0[2], v0[3]);
        unsigned d0p = pack_bf16x2(v1[0], v1[1]);
        unsigned d1p = pack_bf16x2(v1[2], v1[3]);
        // quad-transpose to B-frag (target lane quad qt needs kv 8qt..8qt+7):
        //   p32swap: c0p=[c@q0,c@q1,d@q0,d@q1], d0p=[c@q2,c@q3,d@q2,d@q3]
        //   p16swap: c0p=[c@q0,c@q2,d@q0,d@q2], d0p=[c@q1,c@q3,d@q1,d@q3]
        permswap32(c0p, d0p);
        permswap32(c1p, d1p);
        permswap16(c0p, d0p);
        permswap16(c1p, d1p);
        uint4v wv; wv[0] = c0p; wv[1] = c1p; wv[2] = d0p; wv[3] = d1p;
        return __builtin_bit_cast(short8, wv);
    };

#define KLOAD(K0_, K1_, K2_, K3_, kvo) do {                                  \
        const bf16_t* Kr0_ = Kbase + (size_t)((kvo) + fr) * EMBED;           \
        const bf16_t* Kr1_ = Kr0_ + (size_t)16 * EMBED;                      \
        K0_ = *(const short8*)(Kr0_ + fk);                                   \
        K1_ = *(const short8*)(Kr0_ + 32 + fk);                              \
        K2_ = *(const short8*)(Kr1_ + fk);                                   \
        K3_ = *(const short8*)(Kr1_ + 32 + fk);                              \
    } while (0)

#define ITER(KC0, KC1, KC2, KC3, KN0, KN1, KN2, KN3, DIAGF, PREF) do {       \
        const int kv0 = c << 5;                                              \
        /* V(c) + K(c+1) issued first: consumed after softmax / next iter */ \
        const short8 vf0 = *(const short8*)(Vbase + ((size_t)(fr)      << 11) + kv0 + fk); \
        const short8 vf1 = *(const short8*)(Vbase + ((size_t)(16 + fr) << 11) + kv0 + fk); \
        const short8 vf2 = *(const short8*)(Vbase + ((size_t)(32 + fr) << 11) + kv0 + fk); \
        const short8 vf3 = *(const short8*)(Vbase + ((size_t)(48 + fr) << 11) + kv0 + fk); \
        if (PREF) { KLOAD(KN0, KN1, KN2, KN3, kv0 + 32); }                   \
        floatx4 s00 = {}, s01 = {}, s10 = {}, s11 = {};                      \
        s00 = MFMA16(KC0, aq00, s00); s00 = MFMA16(KC1, aq01, s00);          \
        s10 = MFMA16(KC0, aq10, s10); s10 = MFMA16(KC1, aq11, s10);          \
        s01 = MFMA16(KC2, aq00, s01); s01 = MFMA16(KC3, aq01, s01);          \
        s11 = MFMA16(KC2, aq10, s11); s11 = MFMA16(KC3, aq11, s11);          \
        const short8 pb0 = smax_pb(s00, s01, m0, l0, o0, DIAGF, 0);          \
        const short8 pb1 = smax_pb(s10, s11, m1, l1, o1, DIAGF, 16);         \
        o0[0] = MFMA16(vf0, pb0, o0[0]); o1[0] = MFMA16(vf0, pb1, o1[0]);    \
        o0[1] = MFMA16(vf1, pb0, o0[1]); o1[1] = MFMA16(vf1, pb1, o1[1]);    \
        o0[2] = MFMA16(vf2, pb0, o0[2]); o1[2] = MFMA16(vf2, pb1, o1[2]);    \
        o0[3] = MFMA16(vf3, pb0, o0[3]); o1[3] = MFMA16(vf3, pb1, o1[3]);    \
    } while (0)

    short8 ka0, ka1, ka2, ka3, kb0, kb1, kb2, kb3;
    KLOAD(ka0, ka1, ka2, ka3, c0 << 5);

    int c = c0;
    const int cl = c1 - 1;
    if (cl > c0) {
        for (;;) {                               // hot loop: no mask code
            ITER(ka0, ka1, ka2, ka3, kb0, kb1, kb2, kb3, false, true);
            if (++c == cl) break;
            ITER(kb0, kb1, kb2, kb3, ka0, ka1, ka2, ka3, false, true);
            if (++c == cl) break;
        }
    }
    // last chunk (diagonal iff this wave owns the tile's end)
    if ((c - c0) & 1) { ITER(kb0, kb1, kb2, kb3, ka0, ka1, ka2, ka3, hasdiag, false); }
    else              { ITER(ka0, ka1, ka2, ka3, kb0, kb1, kb2, kb3, hasdiag, false); }

#undef ITER
#undef KLOAD

    // deferred cross-quad l reduction (once)
    { float t = __shfl_xor(l0, 16, 64); l0 += t; t = __shfl_xor(l0, 32, 64); l0 += t; }
    { float t = __shfl_xor(l1, 16, 64); l1 += t; t = __shfl_xor(l1, 32, 64); l1 += t; }

    if (!split) {
        // O^T: lane(fr,quad) holds O[q=fr][d=16t+quad*4+r] -> 8B contiguous stores
        const float i0 = 1.0f / l0;
        const float i1 = 1.0f / l1;
        bf16_t* out0 = AO + (size_t)(b * SEQ + q0 + fr) * EMBED + h * HDIM + (quad << 2);
        bf16_t* out1 = out0 + (size_t)16 * EMBED;
        #pragma unroll
        for (int t = 0; t < 4; ++t) {
            short4v pk0, pk1;
            #pragma unroll
            for (int r = 0; r < 4; ++r) {
                pk0[r] = bf16_bits(o0[t][r] * i0);
                pk1[r] = bf16_bits(o1[t][r] * i1);
            }
            *(short4v*)(out0 + (t << 4)) = pk0;
            *(short4v*)(out1 + (t << 4)) = pk1;
        }
    } else {
        // fp32 partial store: Op[s][p][row][d] (row = u16+fr, d = 16t+quad*4+r)
        const int p = (bh << 5) | (tile - 32);            // 0..1023
        float* Ob = Op + (((size_t)sidx << 10) + p) * 2048;
        #pragma unroll
        for (int t = 0; t < 4; ++t) {
            *(floatx4*)&Ob[fr * 64 + (t << 4) + (quad << 2)]        = o0[t];
            *(floatx4*)&Ob[(16 + fr) * 64 + (t << 4) + (quad << 2)] = o1[t];
        }
        if (quad == 0) {                                  // m,l uniform across quads
            const size_t mb = (((size_t)sidx << 10) + p) * 32;
            Mp[mb + fr]      = m0;
            Mp[mb + 16 + fr] = m1;
            Lp[mb + fr]      = l0;
            Lp[mb + 16 + fr] = l1;
        }
    }
}

// Combine the two kv-half partials of split tiles: O = (O0*w0 + O1*w1)/(l0*w0 + l1*w1),
// w_s = 2^(m_s - M), M = max(m0,m1). One block per tile-instance (p in 0..1023).
__global__ __launch_bounds__(256)
void attn_combine(const float* __restrict__ Op, const float* __restrict__ Mp,
                  const float* __restrict__ Lp, bf16_t* __restrict__ AO)
{
    const int p   = (int)blockIdx.x;          // (bh<<5)|(tile-32)
    const int tid = (int)threadIdx.x;
    const int row = tid >> 3;                 // 0..31
    const int d0  = (tid & 7) << 3;           // 0,8,..,56
    const int bh = p >> 5, tile = 32 + (p & 31);
    const int b = bh >> 4, h = bh & 15;

    const float m0 = Mp[(size_t)p * 32 + row];
    const float m1 = Mp[(size_t)(1024 + p) * 32 + row];
    const float l0 = Lp[(size_t)p * 32 + row];
    const float l1 = Lp[(size_t)(1024 + p) * 32 + row];
    const float M  = fmaxf(m0, m1);
    const float w0 = fast_exp2(m0 - M);
    const float w1 = fast_exp2(m1 - M);
    const float rd = 1.0f / (l0 * w0 + l1 * w1);

    const float* O0 = Op + ((size_t)p << 11) + row * 64 + d0;
    const float* O1 = O0 + ((size_t)1024 << 11);
    const float4 a0 = *(const float4*)O0;
    const float4 a1 = *(const float4*)(O0 + 4);
    const float4 c0 = *(const float4*)O1;
    const float4 c1 = *(const float4*)(O1 + 4);

    short8 pk;
    pk[0] = bf16_bits((a0.x * w0 + c0.x * w1) * rd);
    pk[1] = bf16_bits((a0.y * w0 + c0.y * w1) * rd);
    pk[2] = bf16_bits((a0.z * w0 + c0.z * w1) * rd);
    pk[3] = bf16_bits((a0.w * w0 + c0.w * w1) * rd);
    pk[4] = bf16_bits((a1.x * w0 + c1.x * w1) * rd);
    pk[5] = bf16_bits((a1.y * w0 + c1.y * w1) * rd);
    pk[6] = bf16_bits((a1.z * w0 + c1.z * w1) * rd);
    pk[7] = bf16_bits((a1.w * w0 + c1.w * w1) * rd);
    *(short8*)(AO + (size_t)(b * SEQ + tile * 32 + row) * EMBED + h * HDIM + d0) = pk;
}

extern "C" void kernel_launch(void* const* d_in, const int* in_sizes, int n_in,
                              void* d_out, int out_size, void* d_ws, size_t ws_size,
                              hipStream_t stream)
{
    (void)in_sizes; (void)n_in; (void)out_size; (void)ws_size;
    const float* q  = (const float*)d_in[0];
    const float* k  = (const float*)d_in[1];
    const float* v  = (const float*)d_in[2];
    const float* Wq = (const float*)d_in[3];
    const float* bq = (const float*)d_in[4];
    const float* Wk = (const float*)d_in[5];
    const float* bk = (const float*)d_in[6];
    const float* Wv = (const float*)d_in[7];
    const float* bv = (const float*)d_in[8];
    const float* Wo = (const float*)d_in[9];
    const float* bo = (const float*)d_in[10];
    // d_in[11] = attn_mask: fixed causal tril, handled analytically.

    const size_t NX = (size_t)MTOT * EMBED;   // 4M
    const size_t NW = (size_t)EMBED * EMBED;  // 1M
    bf16_t* Qx  = (bf16_t*)d_ws;
    bf16_t* Kx  = Qx  + NX;
    bf16_t* Vx  = Kx  + NX;
    bf16_t* Wqb = Vx  + NX;
    bf16_t* Wkb = Wqb + NW;
    bf16_t* Wvb = Wkb + NW;
    bf16_t* Wob = Wvb + NW;
    bf16_t* Qp  = Wob + NW;
    bf16_t* Kp  = Qp  + NX;
    bf16_t* Vtp = Kp  + NX;   // transposed: [b*1024 + d_global][s]
    bf16_t* AO  = Vtp + NX;   // total 32M bf16 = 64 MB

    // attn partials overlay buffers that are dead after qkv_proj:
    //   Op (16 MB fp32) over Qx+Kx; Mp/Lp (512 KB) over Wqb.
    float* Op = (float*)Qx;
    float* Mp = (float*)Wqb;
    float* Lp = Mp + 2 * 1024 * 32;

    dim3 blk(256);
    cvt_all<<<dim3(4096, 7), blk, 0, stream>>>(q, k, v, Wq, Wk, Wv, Wo,
                                               Qx, Kx, Vx, Wqb, Wkb, Wvb, Wob);
    qkv_proj<<<dim3(256, 1, 3), blk, 0, stream>>>(Qx, Kx, Vx, Wqb, Wkb, Wvb,
                                                  bq, bk, bv, Qp, Kp, Vtp);
    attn_causal<<<dim3(3072), dim3(64), 0, stream>>>(Qp, Kp, Vtp, AO, Op, Mp, Lp);
    attn_combine<<<dim3(1024), blk, 0, stream>>>(Op, Mp, Lp, AO);
    out_proj<<<dim3(512), blk, 0, stream>>>(AO, Wob, bo, (float*)d_out);
}

// Round 5
// 261.435 us; speedup vs baseline: 1.0967x; 1.0866x over previous
//
#include <hip/hip_runtime.h>
#include <hip/hip_bf16.h>
#include <stdint.h>
#include <stddef.h>

typedef __hip_bfloat16 bf16_t;
typedef __attribute__((ext_vector_type(8))) short short8;
typedef __attribute__((ext_vector_type(4))) short short4v;
typedef __attribute__((ext_vector_type(4))) float floatx4;
typedef __attribute__((ext_vector_type(4))) unsigned uint4v;
typedef __attribute__((ext_vector_type(2))) unsigned uint2v;

#define EMBED 1024
#define NHEAD 16
#define HDIM  64
#define BATCH 2
#define SEQ   2048
#define MTOT  (BATCH*SEQ)
#define NEG_INF (-1e30f)
// 1/sqrt(64) * log2(e): softmax carried in exp2 domain (folded into Q projection)
#define SCALE2 0.18033688011112042f

#define MFMA16(a,b,c) __builtin_amdgcn_mfma_f32_16x16x32_bf16(a,b,c,0,0,0)

static __device__ __forceinline__ short bf16_bits(float x) {
    return __builtin_bit_cast(short, __float2bfloat16(x));
}

static __device__ __forceinline__ float fast_exp2(float x) {
#if __has_builtin(__builtin_amdgcn_exp2f)
    return __builtin_amdgcn_exp2f(x);
#else
    return __expf(x * 0.6931471805599453f);
#endif
}

// two bf16 (RTNE) packed in a u32; compiler fuses to v_cvt_pk_bf16_f32 (m240)
static __device__ __forceinline__ unsigned pack_bf16x2(float lo, float hi) {
    const unsigned a = (unsigned)(unsigned short)bf16_bits(lo);
    const unsigned b = (unsigned)(unsigned short)bf16_bits(hi);
    return a | (b << 16);
}

// gfx950 permlane swaps (verified R4: absmax unchanged vs LDS path)
static __device__ __forceinline__ void permswap32(unsigned& a, unsigned& b) {
#if __has_builtin(__builtin_amdgcn_permlane32_swap)
    uint2v r = __builtin_amdgcn_permlane32_swap(a, b, false, false);
    a = r[0]; b = r[1];
#else
    asm volatile("v_permlane32_swap_b32 %0, %1" : "+v"(a), "+v"(b));
#endif
}
static __device__ __forceinline__ void permswap16(unsigned& a, unsigned& b) {
#if __has_builtin(__builtin_amdgcn_permlane16_swap)
    uint2v r = __builtin_amdgcn_permlane16_swap(a, b, false, false);
    a = r[0]; b = r[1];
#else
    asm volatile("v_permlane16_swap_b32 %0, %1" : "+v"(a), "+v"(b));
#endif
}

// async global->LDS, 16B per lane; lds ptr must be wave-uniform (HW: base + lane*16)
static __device__ __forceinline__ void async_ld16(const bf16_t* g, short* l) {
    __builtin_amdgcn_global_load_lds(
        (const __attribute__((address_space(1))) void*)g,
        (__attribute__((address_space(3))) void*)l,
        16, 0, 0);
}

static __device__ __forceinline__ void store_out(float* p, float v)  { *p = v; }
static __device__ __forceinline__ void store_out(bf16_t* p, float v) { *p = __float2bfloat16(v); }

// fp32 -> bf16 (RTNE) for q,k,v (4M each) and Wq,Wk,Wv,Wo (1M each). grid.y selects tensor.
__global__ __launch_bounds__(256)
void cvt_all(const float* __restrict__ q, const float* __restrict__ k, const float* __restrict__ v,
             const float* __restrict__ wq, const float* __restrict__ wk,
             const float* __restrict__ wv, const float* __restrict__ wo,
             bf16_t* __restrict__ Qx, bf16_t* __restrict__ Kx, bf16_t* __restrict__ Vx,
             bf16_t* __restrict__ Wqb, bf16_t* __restrict__ Wkb,
             bf16_t* __restrict__ Wvb, bf16_t* __restrict__ Wob)
{
    const float* s; bf16_t* d; int n;
    switch (blockIdx.y) {
        case 0:  s = q;  d = Qx;  n = MTOT * EMBED;  break;
        case 1:  s = k;  d = Kx;  n = MTOT * EMBED;  break;
        case 2:  s = v;  d = Vx;  n = MTOT * EMBED;  break;
        case 3:  s = wq; d = Wqb; n = EMBED * EMBED; break;
        case 4:  s = wk; d = Wkb; n = EMBED * EMBED; break;
        case 5:  s = wv; d = Wvb; n = EMBED * EMBED; break;
        default: s = wo; d = Wob; n = EMBED * EMBED; break;
    }
    const int i4 = (int)blockIdx.x * 256 + (int)threadIdx.x;   // float4 index
    if (i4 * 4 < n) {
        const float4 f = ((const float4*)s)[i4];
        short4v o;
        o[0] = bf16_bits(f.x); o[1] = bf16_bits(f.y);
        o[2] = bf16_bits(f.z); o[3] = bf16_bits(f.w);
        ((short4v*)d)[i4] = o;
    }
}

// C[M,N] = (A[M,K] @ W[N,K]^T + bias) * scale, bf16 in, fp32 accumulate.
// M=4096, N=K=1024 fixed. BM x 128 tile, BK=64 (two 32-col half-buffers per barrier
// pair -> half the barrier-drain count vs m97's BK=32; row layout per half unchanged,
// so the verified bank pattern is preserved). 256 thr (4 waves 2x2).
// VT=true: write output transposed per-batch as Ct[b*1024 + n][s] (for V: [b, d_global, s]).
template <typename OutT, bool VT, int BM>
static __device__ __forceinline__ void gemm_tile(
    const bf16_t* __restrict__ A, const bf16_t* __restrict__ W,
    const float* __restrict__ bias, OutT* __restrict__ C, const float scale)
{
    constexpr int MI  = BM >> 5;            // A-frags per wave (4 or 2)
    constexpr int RPW = BM >> 2;            // A rows staged per wave
    const int N = 1024, K = 1024;
    __shared__ alignas(16) short As[2][BM * 32];
    __shared__ alignas(16) short Bs[2][128 * 32];

    const int tid  = threadIdx.x;
    const int wave = tid >> 6;
    const int lane = tid & 63;
    const int bm = (int)blockIdx.x >> 3;    // nbn = 8
    const int bn = (int)blockIdx.x & 7;
    const int m0 = bm * BM, n0 = bn << 7;

    const int wm = ((wave >> 1) & 1) * (BM >> 1);
    const int wn = (wave & 1) << 6;

    floatx4 acc[MI][4] = {};

    const int srowA = wave * RPW + (lane >> 2);
    const int srowB = (wave << 5) + (lane >> 2);
    const int scol  = (lane & 3) << 3;            // element col: 0,8,16,24
    const bf16_t* gA = A + (size_t)(m0 + srowA) * K + scol;
    const bf16_t* gB = W + (size_t)(n0 + srowB) * K + scol;

    const int fr = lane & 15;
    const int fk = (lane >> 4) << 3;

    for (int k0 = 0; k0 < K; k0 += 64) {
        __syncthreads();
        short* a0 = &As[0][wave * RPW * 32];
        short* a1 = &As[1][wave * RPW * 32];
        short* b0 = &Bs[0][wave << 10];
        short* b1 = &Bs[1][wave << 10];
        async_ld16(gA,      a0);
        async_ld16(gA + 32, a1);
        if constexpr (BM == 128) {
            async_ld16(gA + (size_t)16 * K,      a0 + 512);
            async_ld16(gA + (size_t)16 * K + 32, a1 + 512);
        }
        async_ld16(gB,      b0);
        async_ld16(gB + 32, b1);
        async_ld16(gB + (size_t)16 * K,      b0 + 512);
        async_ld16(gB + (size_t)16 * K + 32, b1 + 512);
        gA += 64; gB += 64;
        __syncthreads();                      // drains vmcnt before barrier (m97-verified)

        #pragma unroll
        for (int hh = 0; hh < 2; ++hh) {
            short8 af[MI], bfr[4];
            #pragma unroll
            for (int i = 0; i < MI; ++i)
                af[i] = *(const short8*)&As[hh][(wm + (i << 4) + fr) * 32 + fk];
            #pragma unroll
            for (int j = 0; j < 4; ++j)
                bfr[j] = *(const short8*)&Bs[hh][(wn + (j << 4) + fr) * 32 + fk];
            #pragma unroll
            for (int i = 0; i < MI; ++i)
                #pragma unroll
                for (int j = 0; j < 4; ++j)
                    acc[i][j] = MFMA16(af[i], bfr[j], acc[i][j]);
        }
    }

    // epilogue: C/D layout col=lane&15, row=quad*4+r
    const int q4 = (lane >> 4) << 2;
    #pragma unroll
    for (int j = 0; j < 4; ++j) {
        const int n = n0 + wn + (j << 4) + fr;
        const float bv = bias[n];
        #pragma unroll
        for (int i = 0; i < MI; ++i) {
            const int mb = m0 + wm + (i << 4) + q4;
            if (VT) {
                // transposed store: Ct[(b*1024 + n)][s], s = mb&2047 .. +3 contiguous (8B)
                const int bb = mb >> 11, ss = mb & 2047;
                short4v pk;
                #pragma unroll
                for (int r = 0; r < 4; ++r)
                    pk[r] = bf16_bits((acc[i][j][r] + bv) * scale);
                *(short4v*)((bf16_t*)C + ((size_t)(bb * 1024 + n) << 11) + ss) = pk;
            } else {
                #pragma unroll
                for (int r = 0; r < 4; ++r)
                    store_out(&C[(size_t)(mb + r) * N + n], (acc[i][j][r] + bv) * scale);
            }
        }
    }
}

__global__ __launch_bounds__(256)
void qkv_proj(const bf16_t* __restrict__ xq, const bf16_t* __restrict__ xk,
              const bf16_t* __restrict__ xv,
              const bf16_t* __restrict__ Wq, const bf16_t* __restrict__ Wk,
              const bf16_t* __restrict__ Wv,
              const float* __restrict__ bq, const float* __restrict__ bk,
              const float* __restrict__ bv,
              bf16_t* __restrict__ Qp, bf16_t* __restrict__ Kp, bf16_t* __restrict__ Vtp)
{
    // Q carries the softmax scale (exp2-domain): folded here, free in attn hot loop
    if (blockIdx.z == 0)      gemm_tile<bf16_t, false, 128>(xq, Wq, bq, Qp, SCALE2);
    else if (blockIdx.z == 1) gemm_tile<bf16_t, false, 128>(xk, Wk, bk, Kp, 1.0f);
    else                      gemm_tile<bf16_t, true , 128>(xv, Wv, bv, Vtp, 1.0f);
}

__global__ __launch_bounds__(256)
void out_proj(const bf16_t* __restrict__ AO, const bf16_t* __restrict__ Wo,
              const float* __restrict__ bo, float* __restrict__ out)
{
    gemm_tile<float, false, 64>(AO, Wo, bo, out, 1.0f);
}

// Flash attention, causal. QK^T as S^T = K·Q^T (C-layout: q = lane&15).
// v5: QBLK=64 (4 q-subtiles/wave) to amortize the per-chunk fixed cost (8 K/V
// fragment loads + addressing) over 2x the MFMA work: total chunk-iters halve
// (66.5k -> 33.8k). R1/R2/R4 showed softmax/DS trims don't move time -> the
// fixed cost is the invariant; attack it by amortization.
//  - permlane in-register P^T (R4, verified), O^T layout, defer-max gate,
//    per-lane l partials, K dbuf prefetch at iter top.
//  - tiles 16..31 kv-split 2-ways (fp32 partials + combine); max 32 iters/wave.
//  - 48 work slots/bh interleaved longest-first: g=w/3, r=w%3:
//    r<2 -> split tile 31-g half r (32-g iters); r==2 -> single tile 15-g (32-2g).
//  - diag: last TWO chunks masked via per-subtile offset off_u = u*16 + {0,-32};
//    off<0 fully masks the subtile (exp2(-inf)=0, safe).
__global__ __launch_bounds__(64, 2)
void attn_causal(const bf16_t* __restrict__ Qp, const bf16_t* __restrict__ Kp,
                 const bf16_t* __restrict__ Vt, bf16_t* __restrict__ AO,
                 float* __restrict__ Op, float* __restrict__ Mp, float* __restrict__ Lp)
{
    const int lane = (int)threadIdx.x & 63;
    const int bid  = (int)blockIdx.x;
    const int bh   = bid & 31;           // bh%8 == XCD for all blocks of this head
    const int w    = bid >> 5;           // 0..47 work-slot
    const int g    = w / 3, r3 = w - g * 3;
    int tile, sidx, c0, c1;
    bool split;
    if (r3 < 2) {                        // split tiles 31..16, two kv-halves
        tile  = 31 - g;
        sidx  = r3;
        split = true;
        const int nch = 2 * tile + 2;
        const int h1  = nch >> 1;        // = tile+1
        c0 = sidx ? h1 : 0;
        c1 = sidx ? nch : h1;
    } else {                             // single-wave tiles 15..0
        tile  = 15 - g;
        sidx  = 0;
        split = false;
        c0 = 0;
        c1 = 2 * tile + 2;
    }
    const bool hasdiag = (c1 == 2 * tile + 2);
    const int b = bh >> 4, h = bh & 15;
    const int q0 = tile << 6;

    const int fr   = lane & 15;
    const int quad = lane >> 4;
    const int fk   = quad << 3;

    // Q B-frags for 4 subtiles (rows q0 + u*16 + fr), Q pre-scaled by SCALE2
    const bf16_t* Qb = Qp + (size_t)(b * SEQ + q0 + fr) * EMBED + h * HDIM;
    short8 aq[4][2];
    #pragma unroll
    for (int u = 0; u < 4; ++u) {
        aq[u][0] = *(const short8*)(Qb + (size_t)(u * 16) * EMBED + fk);
        aq[u][1] = *(const short8*)(Qb + (size_t)(u * 16) * EMBED + 32 + fk);
    }

    const bf16_t* Kbase = Kp + (size_t)(b * SEQ) * EMBED + h * HDIM;
    const bf16_t* Vbase = Vt + ((size_t)(b * 1024 + h * HDIM) << 11);

    floatx4 o[4][4] = {};                     // O^T[u][d=t*16+quad*4+r][q=fr]
    float m[4] = {NEG_INF, NEG_INF, NEG_INF, NEG_INF};
    float l[4] = {};

    // Softmax for one subtile -> PV B-frag (P^T[kv][q]) via permlane quad-transpose.
    auto smax_pb = [&](const floatx4& sA, const floatx4& sB, float& m_u, float& l_u,
                       floatx4* o_u, const bool masked, const int off) -> short8 {
        float v0[4], v1[4];
        #pragma unroll
        for (int rr = 0; rr < 4; ++rr) {
            float a  = sA[rr];
            float bb = sB[rr];
            if (masked) {
                const int kq = (quad << 2) + rr;
                if (kq > off + fr)      a  = NEG_INF;
                if (kq + 16 > off + fr) bb = NEG_INF;
            }
            v0[rr] = a; v1[rr] = bb;
        }
        float mx = fmaxf(fmaxf(fmaxf(v0[0], v0[1]), fmaxf(v0[2], v0[3])),
                         fmaxf(fmaxf(v1[0], v1[1]), fmaxf(v1[2], v1[3])));
        if (__any(mx > m_u + 8.0f)) {             // rare path (~once per wave)
            mx = fmaxf(mx, __shfl_xor(mx, 16, 64));
            mx = fmaxf(mx, __shfl_xor(mx, 32, 64));
            const float mn = fmaxf(m_u, mx);
            const float al = fast_exp2(m_u - mn);
            m_u = mn;
            l_u *= al;
            #pragma unroll
            for (int t = 0; t < 4; ++t)           // O^T: q = fr for ALL values
                #pragma unroll
                for (int rr = 0; rr < 4; ++rr) o_u[t][rr] *= al;
        }
        float ls = 0.f;
        #pragma unroll
        for (int rr = 0; rr < 4; ++rr) {
            v0[rr] = fast_exp2(v0[rr] - m_u);     // bounded by 2^8 (defer-max)
            v1[rr] = fast_exp2(v1[rr] - m_u);
            ls += v0[rr] + v1[rr];
        }
        l_u += ls;                                // per-lane partial, no shfl
        unsigned c0p = pack_bf16x2(v0[0], v0[1]);
        unsigned c1p = pack_bf16x2(v0[2], v0[3]);
        unsigned d0p = pack_bf16x2(v1[0], v1[1]);
        unsigned d1p = pack_bf16x2(v1[2], v1[3]);
        permswap32(c0p, d0p);
        permswap32(c1p, d1p);
        permswap16(c0p, d0p);
        permswap16(c1p, d1p);
        uint4v wv; wv[0] = c0p; wv[1] = c1p; wv[2] = d0p; wv[3] = d1p;
        return __builtin_bit_cast(short8, wv);
    };

#define KLOAD(K0_, K1_, K2_, K3_, kvo) do {                                  \
        const bf16_t* Kr0_ = Kbase + (size_t)((kvo) + fr) * EMBED;           \
        const bf16_t* Kr1_ = Kr0_ + (size_t)16 * EMBED;                      \
        K0_ = *(const short8*)(Kr0_ + fk);                                   \
        K1_ = *(const short8*)(Kr0_ + 32 + fk);                              \
        K2_ = *(const short8*)(Kr1_ + fk);                                   \
        K3_ = *(const short8*)(Kr1_ + 32 + fk);                              \
    } while (0)

// CC: chunk index; MASKED/OFFB compile-time; PREF: prefetch chunk CC+1 into KN*
#define ITER(KC0, KC1, KC2, KC3, KN0, KN1, KN2, KN3, CC, MASKED, OFFB, PREF) do { \
        const int kv0 = (CC) << 5;                                           \
        short8 vf[4];                                                        \
        _Pragma("unroll")                                                    \
        for (int t = 0; t < 4; ++t)                                          \
            vf[t] = *(const short8*)(Vbase + ((size_t)((t << 4) + fr) << 11) + kv0 + fk); \
        if (PREF) { KLOAD(KN0, KN1, KN2, KN3, kv0 + 32); }                   \
        floatx4 s0[4], s1[4];                                                \
        _Pragma("unroll")                                                    \
        for (int u = 0; u < 4; ++u) {                                        \
            floatx4 z0 = {}, z1 = {};                                        \
            z0 = MFMA16(KC0, aq[u][0], z0); z0 = MFMA16(KC1, aq[u][1], z0);  \
            z1 = MFMA16(KC2, aq[u][0], z1); z1 = MFMA16(KC3, aq[u][1], z1);  \
            s0[u] = z0; s1[u] = z1;                                          \
        }                                                                    \
        short8 pb[4];                                                        \
        _Pragma("unroll")                                                    \
        for (int u = 0; u < 4; ++u)                                          \
            pb[u] = smax_pb(s0[u], s1[u], m[u], l[u], o[u], MASKED, u * 16 + (OFFB)); \
        _Pragma("unroll")                                                    \
        for (int u = 0; u < 4; ++u)                                          \
            _Pragma("unroll")                                                \
            for (int t = 0; t < 4; ++t)                                      \
                o[u][t] = MFMA16(vf[t], pb[u], o[u][t]);                     \
    } while (0)

    short8 ka0, ka1, ka2, ka3, kb0, kb1, kb2, kb3;
    KLOAD(ka0, ka1, ka2, ka3, c0 << 5);

    int c = c0;
    const int cm = c1 - (hasdiag ? 2 : 1);   // first peeled chunk
    if (cm > c0) {
        for (;;) {                           // hot loop: no mask code
            ITER(ka0, ka1, ka2, ka3, kb0, kb1, kb2, kb3, c, false, 0, true);
            if (++c == cm) break;
            ITER(kb0, kb1, kb2, kb3, ka0, ka1, ka2, ka3, c, false, 0, true);
            if (++c == cm) break;
        }
    }
    const bool ina = (((c - c0) & 1) == 0);  // current chunk's K in ka?
    if (hasdiag) {
        if (ina) {
            ITER(ka0, ka1, ka2, ka3, kb0, kb1, kb2, kb3, c,     true,   0, true);
            ITER(kb0, kb1, kb2, kb3, ka0, ka1, ka2, ka3, c + 1, true, -32, false);
        } else {
            ITER(kb0, kb1, kb2, kb3, ka0, ka1, ka2, ka3, c,     true,   0, true);
            ITER(ka0, ka1, ka2, ka3, kb0, kb1, kb2, kb3, c + 1, true, -32, false);
        }
    } else {
        if (ina) ITER(ka0, ka1, ka2, ka3, kb0, kb1, kb2, kb3, c, false, 0, false);
        else     ITER(kb0, kb1, kb2, kb3, ka0, ka1, ka2, ka3, c, false, 0, false);
    }

#undef ITER
#undef KLOAD

    // deferred cross-quad l reduction (once)
    #pragma unroll
    for (int u = 0; u < 4; ++u) {
        float t = __shfl_xor(l[u], 16, 64); l[u] += t;
        t = __shfl_xor(l[u], 32, 64);       l[u] += t;
    }

    if (!split) {
        // O^T: lane(fr,quad) holds O[q=fr][d=16t+quad*4+r] -> 8B contiguous stores
        #pragma unroll
        for (int u = 0; u < 4; ++u) {
            const float iu = 1.0f / l[u];
            bf16_t* outp = AO + (size_t)(b * SEQ + q0 + u * 16 + fr) * EMBED
                              + h * HDIM + (quad << 2);
            #pragma unroll
            for (int t = 0; t < 4; ++t) {
                short4v pk;
                #pragma unroll
                for (int rr = 0; rr < 4; ++rr)
                    pk[rr] = bf16_bits(o[u][t][rr] * iu);
                *(short4v*)(outp + (t << 4)) = pk;
            }
        }
    } else {
        // fp32 partials: Op[sidx][p][row=u*16+fr][d=t*16+quad*4..+3]
        const int p = (bh << 4) | (tile - 16);            // 0..511
        float* Ob = Op + ((size_t)(sidx * 512 + p)) * 4096;
        #pragma unroll
        for (int u = 0; u < 4; ++u) {
            #pragma unroll
            for (int t = 0; t < 4; ++t)
                *(floatx4*)&Ob[(u * 16 + fr) * 64 + (t << 4) + (quad << 2)] = o[u][t];
        }
        if (quad == 0) {                                  // m,l uniform across quads
            const size_t mb = (size_t)(sidx * 512 + p) * 64;
            #pragma unroll
            for (int u = 0; u < 4; ++u) {
                Mp[mb + u * 16 + fr] = m[u];
                Lp[mb + u * 16 + fr] = l[u];
            }
        }
    }
}

// Combine the two kv-half partials of split tiles (16..31):
// O = (O0*w0 + O1*w1)/(l0*w0 + l1*w1), w_s = 2^(m_s - M).
// One block per tile-instance p in 0..511; 256 thr: row=tid>>2, d-seg=(tid&3)*16.
__global__ __launch_bounds__(256)
void attn_combine(const float* __restrict__ Op, const float* __restrict__ Mp,
                  const float* __restrict__ Lp, bf16_t* __restrict__ AO)
{
    const int p   = (int)blockIdx.x;          // (bh<<4)|(tile-16)
    const int tid = (int)threadIdx.x;
    const int row = tid >> 2;                 // 0..63
    const int d0  = (tid & 3) << 4;           // 0,16,32,48
    const int bh = p >> 4, tile = 16 + (p & 15);
    const int b = bh >> 4, h = bh & 15;

    const float m0 = Mp[(size_t)p * 64 + row];
    const float m1 = Mp[(size_t)(512 + p) * 64 + row];
    const float l0 = Lp[(size_t)p * 64 + row];
    const float l1 = Lp[(size_t)(512 + p) * 64 + row];
    const float M  = fmaxf(m0, m1);
    const float w0 = fast_exp2(m0 - M);
    const float w1 = fast_exp2(m1 - M);
    const float rd = 1.0f / (l0 * w0 + l1 * w1);

    const float* O0 = Op + (size_t)p * 4096 + row * 64 + d0;
    const float* O1 = O0 + (size_t)512 * 4096;
    bf16_t* outp = AO + (size_t)(b * SEQ + tile * 64 + row) * EMBED + h * HDIM + d0;

    #pragma unroll
    for (int seg = 0; seg < 2; ++seg) {       // two 8-float segments -> two short8
        const float4 a0 = *(const float4*)(O0 + seg * 8);
        const float4 a1 = *(const float4*)(O0 + seg * 8 + 4);
        const float4 c0 = *(const float4*)(O1 + seg * 8);
        const float4 c1 = *(const float4*)(O1 + seg * 8 + 4);
        short8 pk;
        pk[0] = bf16_bits((a0.x * w0 + c0.x * w1) * rd);
        pk[1] = bf16_bits((a0.y * w0 + c0.y * w1) * rd);
        pk[2] = bf16_bits((a0.z * w0 + c0.z * w1) * rd);
        pk[3] = bf16_bits((a0.w * w0 + c0.w * w1) * rd);
        pk[4] = bf16_bits((a1.x * w0 + c1.x * w1) * rd);
        pk[5] = bf16_bits((a1.y * w0 + c1.y * w1) * rd);
        pk[6] = bf16_bits((a1.z * w0 + c1.z * w1) * rd);
        pk[7] = bf16_bits((a1.w * w0 + c1.w * w1) * rd);
        *(short8*)(outp + seg * 8) = pk;
    }
}

extern "C" void kernel_launch(void* const* d_in, const int* in_sizes, int n_in,
                              void* d_out, int out_size, void* d_ws, size_t ws_size,
                              hipStream_t stream)
{
    (void)in_sizes; (void)n_in; (void)out_size; (void)ws_size;
    const float* q  = (const float*)d_in[0];
    const float* k  = (const float*)d_in[1];
    const float* v  = (const float*)d_in[2];
    const float* Wq = (const float*)d_in[3];
    const float* bq = (const float*)d_in[4];
    const float* Wk = (const float*)d_in[5];
    const float* bk = (const float*)d_in[6];
    const float* Wv = (const float*)d_in[7];
    const float* bv = (const float*)d_in[8];
    const float* Wo = (const float*)d_in[9];
    const float* bo = (const float*)d_in[10];
    // d_in[11] = attn_mask: fixed causal tril, handled analytically.

    const size_t NX = (size_t)MTOT * EMBED;   // 4M
    const size_t NW = (size_t)EMBED * EMBED;  // 1M
    bf16_t* Qx  = (bf16_t*)d_ws;
    bf16_t* Kx  = Qx  + NX;
    bf16_t* Vx  = Kx  + NX;
    bf16_t* Wqb = Vx  + NX;
    bf16_t* Wkb = Wqb + NW;
    bf16_t* Wvb = Wkb + NW;
    bf16_t* Wob = Wvb + NW;
    bf16_t* Qp  = Wob + NW;
    bf16_t* Kp  = Qp  + NX;
    bf16_t* Vtp = Kp  + NX;   // transposed: [b*1024 + d_global][s]
    bf16_t* AO  = Vtp + NX;   // total 32M bf16 = 64 MB

    // attn partials overlay buffers dead after qkv_proj:
    //   Op (16 MB fp32 = 2*512*4096*4B) over Qx+Kx; Mp/Lp (128 KB each) over Wqb.
    float* Op = (float*)Qx;
    float* Mp = (float*)Wqb;
    float* Lp = Mp + 2 * 512 * 64;

    dim3 blk(256);
    cvt_all<<<dim3(4096, 7), blk, 0, stream>>>(q, k, v, Wq, Wk, Wv, Wo,
                                               Qx, Kx, Vx, Wqb, Wkb, Wvb, Wob);
    qkv_proj<<<dim3(256, 1, 3), blk, 0, stream>>>(Qx, Kx, Vx, Wqb, Wkb, Wvb,
                                                  bq, bk, bv, Qp, Kp, Vtp);
    attn_causal<<<dim3(1536), dim3(64), 0, stream>>>(Qp, Kp, Vtp, AO, Op, Mp, Lp);
    attn_combine<<<dim3(512), blk, 0, stream>>>(Op, Mp, Lp, AO);
    out_proj<<<dim3(512), blk, 0, stream>>>(AO, Wob, bo, (float*)d_out);
}